// Round 4
// baseline (450.180 us; speedup 1.0000x reference)
//
#include <hip/hip_runtime.h>

typedef unsigned short u16;
typedef unsigned int u32;
typedef __bf16 bf16x8 __attribute__((ext_vector_type(8)));
typedef float f32x4 __attribute__((ext_vector_type(4)));

#if defined(__has_builtin)
#  if __has_builtin(__builtin_amdgcn_cvt_pk_bf16_f32)
#    define PK_BF16 1
#  endif
#endif

__device__ __forceinline__ u16 f2bu(float f){
  u32 u = __float_as_uint(f);
  return (u16)((u + 0x7fffu + ((u >> 16) & 1u)) >> 16);
}
__device__ __forceinline__ float b2f(u16 u){
  union { float f; u32 i; } v; v.i = ((u32)u) << 16; return v.f;
}
__device__ __forceinline__ u32 pkbf(float a, float b){
#ifdef PK_BF16
  typedef __bf16 bf16x2 __attribute__((ext_vector_type(2)));
  union { bf16x2 h; u32 u; } c;
  c.h = __builtin_amdgcn_cvt_pk_bf16_f32(a, b);
  return c.u;
#else
  return (u32)f2bu(a) | ((u32)f2bu(b) << 16);
#endif
}
// async global->LDS, 16B per lane; LDS dest = wave-uniform base + lane*16
__device__ __forceinline__ void glds16(const u16* g, u16* l){
  __builtin_amdgcn_global_load_lds(
      (const __attribute__((address_space(1))) void*)g,
      (__attribute__((address_space(3))) void*)l, 16, 0, 0);
}

// ---------------------------------------------------------------------------
// prep_wc: Wc[384][320] bf16 = Wp + 1e-5*Wm (zero padded), bc[384] f32
// ---------------------------------------------------------------------------
__global__ __launch_bounds__(256) void prep_wc(
    const float* __restrict__ Wp, const float* __restrict__ bp,
    const float* __restrict__ Wm, const float* __restrict__ bm,
    u16* __restrict__ Wc, float* __restrict__ bc)
{
  int idx = blockIdx.x * 256 + threadIdx.x;   // bf16-pair index
  if (idx < 384 * 160) {
    int n = idx / 160, k = (idx % 160) * 2;
    float v0 = 0.f, v1 = 0.f;
    if (n < 300 && k < 300) {
      v0 = Wp[n * 300 + k]     + 1e-5f * Wm[n * 300 + k];
      v1 = Wp[n * 300 + k + 1] + 1e-5f * Wm[n * 300 + k + 1];
    }
    ((u32*)Wc)[idx] = pkbf(v0, v1);
    if (idx < 384) bc[idx] = (idx < 300) ? bp[idx] + 1e-5f * bm[idx] : 0.f;
  }
}

// ---------------------------------------------------------------------------
// prep_wv16: wv16[30000][320] bf16 copy of wv (cols 300..319 zero)
// ---------------------------------------------------------------------------
__global__ __launch_bounds__(256) void prep_wv16(
    const float* __restrict__ wv, u16* __restrict__ wv16)
{
  int idx = blockIdx.x * 256 + threadIdx.x;   // pair index
  if (idx < 30000 * 160) {
    int row = idx / 160, k = (idx % 160) * 2;
    float v0 = 0.f, v1 = 0.f;
    if (k < 300) {
      v0 = wv[(size_t)row * 300 + k];
      v1 = wv[(size_t)row * 300 + k + 1];
    }
    ((u32*)wv16)[idx] = pkbf(v0, v1);
  }
}

// ---------------------------------------------------------------------------
// prep_wf16: Wf[300][2048] f32 -> Wf16[384][2048] bf16 (rows 300..383 zero)
// ---------------------------------------------------------------------------
__global__ __launch_bounds__(256) void prep_wf16(
    const float* __restrict__ Wf, u16* __restrict__ Wf16)
{
  int i = blockIdx.x * 256 + threadIdx.x;   // pair index, 384*1024 total
  if (i < 384 * 1024) {
    int row = i >> 10, c2 = (i & 1023) * 2;
    float v0 = 0.f, v1 = 0.f;
    if (row < 300) {
      v0 = Wf[(size_t)row * 2048 + c2];
      v1 = Wf[(size_t)row * 2048 + c2 + 1];
    }
    ((u32*)Wf16)[i] = pkbf(v0, v1);
  }
}

// ---------------------------------------------------------------------------
// gemm0 fallback (no workspace): f32 sources, cvt in staging, 128x128 tile.
// ---------------------------------------------------------------------------
template <int GLDS>
__global__ __launch_bounds__(256) void gemm0_kernel(
    const float* __restrict__ A, const float* __restrict__ B,
    const u16* __restrict__ Af16, const u16* __restrict__ Bf16,
    const float* __restrict__ bias,
    const int* __restrict__ label, const float* __restrict__ wv,
    float* __restrict__ C, u16* __restrict__ kemb16)
{
  __shared__ __align__(16) u16 As[128 * 32];
  __shared__ __align__(16) u16 Bs[128 * 32];
  const int lda = 2048, K = 2048, nbn = 3, nsrc = 300;
  int t = threadIdx.x;
  int bm = (blockIdx.x / nbn) * 128;
  int bn = (blockIdx.x % nbn) * 128;
  int lane = t & 63, w = t >> 6;
  int wm = (w >> 1) * 64, wn = (w & 1) * 64;

  f32x4 acc[4][4];
  for (int i = 0; i < 4; i++)
    for (int j = 0; j < 4; j++)
      for (int r = 0; r < 4; r++) acc[i][j][r] = 0.f;

  int mrow = lane & 15, q = lane >> 4;

  for (int kk = 0; kk < K; kk += 32) {
    #pragma unroll
    for (int p = 0; p < 2; p++) {
      int idx = t + p * 256;
      int row = idx >> 2, ch = idx & 3;
      int brow = bn + row;
      if (brow >= nsrc) brow = 0;  // clamp; masked at store
      const float4* ap = (const float4*)&A[(size_t)(bm + row) * lda + kk + ch * 8];
      float4 a0 = ap[0], a1 = ap[1];
      const float4* bpp = (const float4*)&B[(size_t)brow * lda + kk + ch * 8];
      float4 b0 = bpp[0], b1 = bpp[1];
      union { u32 u[4]; uint4 v; } pa, pb;
      pa.u[0] = pkbf(a0.x, a0.y); pa.u[1] = pkbf(a0.z, a0.w);
      pa.u[2] = pkbf(a1.x, a1.y); pa.u[3] = pkbf(a1.z, a1.w);
      pb.u[0] = pkbf(b0.x, b0.y); pb.u[1] = pkbf(b0.z, b0.w);
      pb.u[2] = pkbf(b1.x, b1.y); pb.u[3] = pkbf(b1.z, b1.w);
      *(uint4*)&As[idx * 8] = pa.v;
      *(uint4*)&Bs[idx * 8] = pb.v;
    }
    __syncthreads();

    bf16x8 af[4], bfr[4];
    #pragma unroll
    for (int i = 0; i < 4; i++)
      af[i] = *(const bf16x8*)&As[(wm + i * 16 + mrow) * 32 + q * 8];
    #pragma unroll
    for (int j = 0; j < 4; j++)
      bfr[j] = *(const bf16x8*)&Bs[(wn + j * 16 + mrow) * 32 + q * 8];
    #pragma unroll
    for (int i = 0; i < 4; i++)
      #pragma unroll
      for (int j = 0; j < 4; j++)
        acc[i][j] = __builtin_amdgcn_mfma_f32_16x16x32_bf16(
            af[i], bfr[j], acc[i][j], 0, 0, 0);
    __syncthreads();
  }

  // epilogue: C/D layout col=lane&15, row=(lane>>4)*4+reg
  #pragma unroll
  for (int i = 0; i < 4; i++)
    #pragma unroll
    for (int j = 0; j < 4; j++) {
      int col = bn + wn + j * 16 + (lane & 15);
      int rb = bm + wm + i * 16 + (lane >> 4) * 4;
      #pragma unroll
      for (int r = 0; r < 4; r++) {
        int m = rb + r;
        if (col < 300) {
          float v = acc[i][j][r];
          v += bias[col] + wv[(size_t)label[m] * 300 + col];
          C[(size_t)m * 300 + col] = v;
          if (kemb16) kemb16[(size_t)m * 320 + col] = f2bu(v);
        } else if (kemb16 && col < 320) {
          kemb16[(size_t)m * 320 + col] = 0;
        }
      }
    }
}

// ---------------------------------------------------------------------------
// gemm0 v4: k_emb = feature @ Wf16^T + bf + wv[label]
//   BARRIER-FREE / LDS-FREE register GEMM.
//   Diagnosis of v3 (125us): 4700 cyc/iter vs ~500 active — the per-K-step
//   __syncthreads (vmcnt(0) drain) serialized an HBM round-trip; depth-1
//   prefetch couldn't hide it; VALUBusy 30% == 3 blocks x 500/4700.
//   Fix: B (wf16, 1.5 MB) is L2-resident; A fragments are read exactly once
//   per wave and are contiguous. So skip LDS: each wave streams A (f32 ->
//   cvt_pk) and B (bf16) straight from global into MFMA. No barriers ->
//   compiler freely software-pipelines the unrolled K-loop; waves never
//   stall as a group.
//   Block = 128M x 64N, 4 waves stacked in M (wave tile 32x64, 8 MFMA/step).
//   Grid 768 = 3 blocks/CU. XCD mapping: each XCD owns 16 M-panels x 6 N,
//   so a panel's 6 N-blocks share that XCD's L2 for the A re-reads.
// ---------------------------------------------------------------------------
__global__ __launch_bounds__(256, 4) void gemm0v4_kernel(
    const float* __restrict__ A, const u16* __restrict__ Bf16,
    const float* __restrict__ bias, const int* __restrict__ label,
    const float* __restrict__ wv, float* __restrict__ C,
    u16* __restrict__ kemb16)
{
  int t = threadIdx.x;
  int lane = t & 63, w = t >> 6;
  int g = blockIdx.x;
  int xcd = g & 7, loc = g >> 3;            // dispatch round-robins XCDs
  int mloc = loc / 6, nn = loc % 6;         // 16 M-panels x 6 N per XCD
  int bm = (xcd * 16 + mloc) * 128;
  int bn = nn * 64;
  int mrow = lane & 15, q = lane >> 4;
  int wm = w * 32;

  f32x4 acc[2][4];
  #pragma unroll
  for (int i = 0; i < 2; i++)
    #pragma unroll
    for (int j = 0; j < 4; j++)
      #pragma unroll
      for (int r = 0; r < 4; r++) acc[i][j][r] = 0.f;

  // per-lane stream pointers (advance via imm offsets inside unroll-8)
  const float* pa0 = &A[(size_t)(bm + wm + mrow) * 2048 + q * 8];
  const float* pa1 = pa0 + (size_t)16 * 2048;
  const u16*   pb0 = &Bf16[(size_t)(bn + mrow) * 2048 + q * 8];
  const u16*   pb1 = pb0 + (size_t)16 * 2048;
  const u16*   pb2 = pb0 + (size_t)32 * 2048;
  const u16*   pb3 = pb0 + (size_t)48 * 2048;

  for (int kk = 0; kk < 2048; kk += 256) {
    #pragma unroll
    for (int s = 0; s < 8; s++) {
      int off = kk + s * 32;                 // A: s*128B, B: s*64B imm-foldable
      f32x4 a00 = *(const f32x4*)(pa0 + off);
      f32x4 a01 = *(const f32x4*)(pa0 + off + 4);
      f32x4 a10 = *(const f32x4*)(pa1 + off);
      f32x4 a11 = *(const f32x4*)(pa1 + off + 4);
      bf16x8 b0 = *(const bf16x8*)(pb0 + off);
      bf16x8 b1 = *(const bf16x8*)(pb1 + off);
      bf16x8 b2 = *(const bf16x8*)(pb2 + off);
      bf16x8 b3 = *(const bf16x8*)(pb3 + off);
      union { u32 u[4]; bf16x8 h; } fa0, fa1;
      fa0.u[0] = pkbf(a00[0], a00[1]); fa0.u[1] = pkbf(a00[2], a00[3]);
      fa0.u[2] = pkbf(a01[0], a01[1]); fa0.u[3] = pkbf(a01[2], a01[3]);
      fa1.u[0] = pkbf(a10[0], a10[1]); fa1.u[1] = pkbf(a10[2], a10[3]);
      fa1.u[2] = pkbf(a11[0], a11[1]); fa1.u[3] = pkbf(a11[2], a11[3]);
      acc[0][0] = __builtin_amdgcn_mfma_f32_16x16x32_bf16(fa0.h, b0, acc[0][0], 0, 0, 0);
      acc[0][1] = __builtin_amdgcn_mfma_f32_16x16x32_bf16(fa0.h, b1, acc[0][1], 0, 0, 0);
      acc[0][2] = __builtin_amdgcn_mfma_f32_16x16x32_bf16(fa0.h, b2, acc[0][2], 0, 0, 0);
      acc[0][3] = __builtin_amdgcn_mfma_f32_16x16x32_bf16(fa0.h, b3, acc[0][3], 0, 0, 0);
      acc[1][0] = __builtin_amdgcn_mfma_f32_16x16x32_bf16(fa1.h, b0, acc[1][0], 0, 0, 0);
      acc[1][1] = __builtin_amdgcn_mfma_f32_16x16x32_bf16(fa1.h, b1, acc[1][1], 0, 0, 0);
      acc[1][2] = __builtin_amdgcn_mfma_f32_16x16x32_bf16(fa1.h, b2, acc[1][2], 0, 0, 0);
      acc[1][3] = __builtin_amdgcn_mfma_f32_16x16x32_bf16(fa1.h, b3, acc[1][3], 0, 0, 0);
    }
  }

  // epilogue: C/D layout col=lane&15, row=(lane>>4)*4+reg
  #pragma unroll
  for (int i = 0; i < 2; i++)
    #pragma unroll
    for (int j = 0; j < 4; j++) {
      int col = bn + j * 16 + (lane & 15);
      int rb = bm + wm + i * 16 + (lane >> 4) * 4;
      #pragma unroll
      for (int r = 0; r < 4; r++) {
        int m = rb + r;
        if (col < 300) {
          float v = acc[i][j][r] + bias[col] + wv[(size_t)label[m] * 300 + col];
          C[(size_t)m * 300 + col] = v;
          kemb16[(size_t)m * 320 + col] = f2bu(v);
        } else if (col < 320) {
          kemb16[(size_t)m * 320 + col] = 0;
        }
      }
    }
}

// ---------------------------------------------------------------------------
// attn (MFMA): block = (b, half of 16 y) -> 192 qwords x 64 keys, K=320.
// ke bf16 in LDS stride 344; A frags straight from wv16 (FULL) with depth-1
// prefetch, or from wv f32 (fallback). Softmax via shfl (1/sum-exp identity),
// word-softmax/5, vectorized p_raw -> praw bf16 [row][320].
// ---------------------------------------------------------------------------
#define KES 344
template <int FULL>
__global__ __launch_bounds__(256) void attn_kernel(
    const float* __restrict__ wv, const u16* __restrict__ wv16,
    const int* __restrict__ query,
    const float* __restrict__ kout, const u16* __restrict__ kemb16,
    u16* __restrict__ praw)
{
  __shared__ __align__(16) u16 ke[64 * KES];
  __shared__ __align__(16) int qoff[192];
  __shared__ __align__(16) float awd[192];
  __shared__ __align__(16) float wt[192];

  int blk = blockIdx.x, b = blk >> 1, bh = blk & 1;
  int t = threadIdx.x;
  int lane = t & 63, w = t >> 6;

  if (FULL) {
    for (int i = t; i < 2560; i += 256) {          // uint4 chunks of 8 cols
      int row = i / 40, ch = i % 40;
      *(uint4*)&ke[row * KES + ch * 8] =
          *(const uint4*)&kemb16[(size_t)(b * 64 + row) * 320 + ch * 8];
    }
  } else {
    for (int i = t; i < 4800; i += 256) {          // float4 chunks of 4 cols
      int row = i / 75, c4 = i % 75;
      float4 v = *(const float4*)&kout[(size_t)(b * 64 + row) * 300 + c4 * 4];
      *(u32*)&ke[row * KES + c4 * 4]     = pkbf(v.x, v.y);
      *(u32*)&ke[row * KES + c4 * 4 + 2] = pkbf(v.z, v.w);
    }
    for (int i = t; i < 640; i += 256) {           // zero cols 300..319
      int row = i / 10, c2 = i % 10;
      *(u32*)&ke[row * KES + 300 + c2 * 2] = 0;
    }
  }
  if (t < 192)
    qoff[t] = query[b * 384 + bh * 192 + t] * (FULL ? 320 : 300);
  __syncthreads();

  int mrow = lane & 15, q = lane >> 4;
  f32x4 acc[3][4];
  #pragma unroll
  for (int i = 0; i < 3; i++)
    #pragma unroll
    for (int j = 0; j < 4; j++)
      #pragma unroll
      for (int r = 0; r < 4; r++) acc[i][j][r] = 0.f;

  int base[3];
  #pragma unroll
  for (int i = 0; i < 3; i++) base[i] = qoff[w * 48 + i * 16 + mrow];
  int keb = mrow * KES + q * 8;

  bf16x8 afn[3];
  #pragma unroll
  for (int i = 0; i < 3; i++) {
    if (FULL)
      afn[i] = *(const bf16x8*)&wv16[(size_t)base[i] + q * 8];
  }

  for (int k0 = 0; k0 < 320; k0 += 32) {
    bf16x8 af[3], bfr[4];
    #pragma unroll
    for (int i = 0; i < 3; i++) {
      if (FULL) {
        af[i] = afn[i];
        if (k0 + 32 < 320)      // depth-1 prefetch
          afn[i] = *(const bf16x8*)&wv16[(size_t)base[i] + k0 + 32 + q * 8];
      } else {
        int cs = k0 + q * 8;
        union { u32 u[4]; bf16x8 h; } c;
        if (cs + 8 <= 300) {
          const float4* p = (const float4*)&wv[(size_t)base[i] + cs];
          float4 x = p[0], y = p[1];
          c.u[0] = pkbf(x.x, x.y); c.u[1] = pkbf(x.z, x.w);
          c.u[2] = pkbf(y.x, y.y); c.u[3] = pkbf(y.z, y.w);
        } else if (cs < 300) {   // cs == 296
          float4 x = *(const float4*)&wv[(size_t)base[i] + 296];
          c.u[0] = pkbf(x.x, x.y); c.u[1] = pkbf(x.z, x.w);
          c.u[2] = 0; c.u[3] = 0;
        } else {
          c.u[0] = 0; c.u[1] = 0; c.u[2] = 0; c.u[3] = 0;
        }
        af[i] = c.h;
      }
    }
    #pragma unroll
    for (int j = 0; j < 4; j++)
      bfr[j] = *(const bf16x8*)&ke[j * 16 * KES + keb + k0];
    #pragma unroll
    for (int i = 0; i < 3; i++)
      #pragma unroll
      for (int j = 0; j < 4; j++)
        acc[i][j] = __builtin_amdgcn_mfma_f32_16x16x32_bf16(
            af[i], bfr[j], acc[i][j], 0, 0, 0);
  }

  // per-word softmax-over-keys: a_w = 1/sum_k exp(scale*(att-max))
  const float scale = 0.05773502691896258f;   // 1/sqrt(300)
  #pragma unroll
  for (int i = 0; i < 3; i++)
    #pragma unroll
    for (int r = 0; r < 4; r++) {
      float mx = fmaxf(fmaxf(acc[i][0][r], acc[i][1][r]),
                       fmaxf(acc[i][2][r], acc[i][3][r]));
      #pragma unroll
      for (int d = 1; d < 16; d <<= 1)
        mx = fmaxf(mx, __shfl_xor(mx, d));
      float se = 0.f;
      #pragma unroll
      for (int j = 0; j < 4; j++)
        se += __expf((acc[i][j][r] - mx) * scale);
      #pragma unroll
      for (int d = 1; d < 16; d <<= 1)
        se += __shfl_xor(se, d);
      if (mrow == 0) {
        int wl = w * 48 + i * 16 + q * 4 + r;
        awd[wl] = (qoff[wl] == 0) ? -3.402823466e38f : (1.0f / se);
      }
    }
  __syncthreads();

  // per-y softmax over 12 words, /5
  if (t < 16) {
    int yb = t * 12;
    float m2 = -3.402823466e38f;
    for (int i = 0; i < 12; i++) m2 = fmaxf(m2, awd[yb + i]);
    float e[12], s2 = 0.f;
    for (int i = 0; i < 12; i++) { e[i] = __expf(awd[yb + i] - m2); s2 += e[i]; }
    float inv = 0.2f / s2;
    for (int i = 0; i < 12; i++) wt[yb + i] = e[i] * inv;
  }
  __syncthreads();

  // p_raw: wave w -> 4 y's
  #pragma unroll
  for (int yy = 0; yy < 4; yy++) {
    int yl = w * 4 + yy;
    int row = b * 32 + bh * 16 + yl;
    if (FULL) {
      if (lane < 40) {     // lane covers 8 cols; 40*8 = 320
        float s[8];
        #pragma unroll
        for (int e = 0; e < 8; e++) s[e] = 0.f;
        for (int i = 0; i < 12; i++) {
          float g = wt[yl * 12 + i];
          union { uint4 v; u16 h[8]; } qv;
          qv.v = *(const uint4*)&wv16[(size_t)qoff[yl * 12 + i] + lane * 8];
          #pragma unroll
          for (int e = 0; e < 8; e++) s[e] += g * b2f(qv.h[e]);
        }
        union { uint4 v; u16 h[8]; } o;
        #pragma unroll
        for (int e = 0; e < 8; e++) o.h[e] = f2bu(s[e]);
        *(uint4*)&praw[(size_t)row * 320 + lane * 8] = o.v;
      }
    } else {
      #pragma unroll
      for (int c = 0; c < 5; c++) {
        int d = c * 64 + lane;
        float s = 0.f;
        if (d < 300)
          for (int i = 0; i < 12; i++)
            s += wt[yl * 12 + i] * wv[(size_t)qoff[yl * 12 + i] + d];
        praw[(size_t)row * 320 + d] = f2bu(s);
      }
    }
  }
}

// ---------------------------------------------------------------------------
// proj (MFMA + glds): p_emb[8192][300] = praw(bf16) @ Wc(bf16)^T + bc -> f32
// ---------------------------------------------------------------------------
__global__ __launch_bounds__(256) void proj_kernel(
    const u16* __restrict__ praw, const u16* __restrict__ Wc,
    const float* __restrict__ bc, float* __restrict__ P)
{
  __shared__ __align__(16) u16 As[128 * 32];
  __shared__ __align__(16) u16 Bs[128 * 32];
  int t = threadIdx.x;
  int bm = (blockIdx.x / 3) * 128;
  int bn = (blockIdx.x % 3) * 128;
  int lane = t & 63, w = t >> 6;
  int wm = (w >> 1) * 64, wn = (w & 1) * 64;

  f32x4 acc[4][4];
  for (int i = 0; i < 4; i++)
    for (int j = 0; j < 4; j++)
      for (int r = 0; r < 4; r++) acc[i][j][r] = 0.f;

  int mrow = lane & 15, q = lane >> 4;

  for (int kk = 0; kk < 320; kk += 32) {
    int r0 = w * 32;
    int rl = lane >> 2, ch = lane & 3;
    #pragma unroll
    for (int p = 0; p < 2; p++) {
      int row = r0 + p * 16 + rl;
      glds16(&praw[(size_t)(bm + row) * 320 + kk + ch * 8],
             &As[(r0 + p * 16) * 32]);
      glds16(&Wc[(size_t)(bn + row) * 320 + kk + ch * 8],
             &Bs[(r0 + p * 16) * 32]);
    }
    __syncthreads();

    bf16x8 af[4], bfr[4];
    #pragma unroll
    for (int i = 0; i < 4; i++)
      af[i] = *(const bf16x8*)&As[(wm + i * 16 + mrow) * 32 + q * 8];
    #pragma unroll
    for (int j = 0; j < 4; j++)
      bfr[j] = *(const bf16x8*)&Bs[(wn + j * 16 + mrow) * 32 + q * 8];
    #pragma unroll
    for (int i = 0; i < 4; i++)
      #pragma unroll
      for (int j = 0; j < 4; j++)
        acc[i][j] = __builtin_amdgcn_mfma_f32_16x16x32_bf16(
            af[i], bfr[j], acc[i][j], 0, 0, 0);
    __syncthreads();
  }

  #pragma unroll
  for (int i = 0; i < 4; i++)
    #pragma unroll
    for (int j = 0; j < 4; j++) {
      int col = bn + wn + j * 16 + (lane & 15);
      if (col >= 300) continue;
      int rb = bm + wm + i * 16 + (lane >> 4) * 4;
      #pragma unroll
      for (int r = 0; r < 4; r++)
        P[(size_t)(rb + r) * 300 + col] = acc[i][j][r] + bc[col];
    }
}

// ---------------------------------------------------------------------------
extern "C" void kernel_launch(void* const* d_in, const int* in_sizes, int n_in,
                              void* d_out, int out_size, void* d_ws,
                              size_t ws_size, hipStream_t stream)
{
  const float* wv      = (const float*)d_in[0];   // [30000,300] f32
  const float* Wf      = (const float*)d_in[1];   // [300,2048]  f32
  const float* bf      = (const float*)d_in[2];   // [300]       f32
  const float* Wp      = (const float*)d_in[3];   // [300,300]   f32
  const float* bp      = (const float*)d_in[4];   // [300]       f32
  const float* Wm      = (const float*)d_in[5];   // [300,300]   f32
  const float* bm      = (const float*)d_in[6];   // [300]       f32
  const float* feature = (const float*)d_in[7];   // [256,64,2048] f32
  const int*   query   = (const int*)d_in[8];     // [256,32,12]
  const int*   label   = (const int*)d_in[9];     // [256,64]

  float* out   = (float*)d_out;     // f32 output
  float* p_out = out;               // p_emb: 8192*300
  float* k_out = out + 2457600;     // k_emb: 16384*300

  char* ws = (char*)d_ws;
  // T2 layout (feature16 slot unused - gemm0v4 reads f32 feature directly):
  //   (unused):           0  (67,108,864)
  //   wv16:      67,108,864  (19,200,000)
  //   kemb16:    86,308,864  (10,485,760)
  //   praw:      96,794,624  ( 5,242,880)
  //   Wc:       102,037,504  (   245,760)
  //   Wf16:     102,283,264  ( 1,572,864)
  //   bc:       103,856,128  (     1,536)
  int t2 = ws_size >= (size_t)103857664;
  int t1 = ws_size >= (size_t)35175936;
  u16 *wf16 = 0, *wv16 = 0, *kemb16 = 0, *praw, *Wc;
  float* bc;
  if (t2) {
    wv16   = (u16*)(ws + 67108864);
    kemb16 = (u16*)(ws + 86308864);
    praw   = (u16*)(ws + 96794624);
    Wc     = (u16*)(ws + 102037504);
    wf16   = (u16*)(ws + 102283264);
    bc     = (float*)(ws + 103856128);
  } else if (t1) {
    wv16   = (u16*)ws;                    // 19,200,000
    kemb16 = (u16*)(ws + 19200000);       // 10,485,760
    praw   = (u16*)(ws + 29685760);       //  5,242,880
    Wc     = (u16*)(ws + 34928640);       //    245,760
    bc     = (float*)(ws + 35174400);
  } else {
    praw   = (u16*)ws;
    Wc     = (u16*)(ws + 5242880);
    bc     = (float*)(ws + 5488640);
  }

  prep_wc<<<240, 256, 0, stream>>>(Wp, bp, Wm, bm, Wc, bc);
  if (t1 || t2)
    prep_wv16<<<18750, 256, 0, stream>>>(wv, wv16);
  if (t2) {
    prep_wf16<<<1536, 256, 0, stream>>>(Wf, wf16);
    gemm0v4_kernel<<<768, 256, 0, stream>>>(feature, wf16, bf,
                                            label, wv, k_out, kemb16);
  } else {
    gemm0_kernel<0><<<384, 256, 0, stream>>>(feature, Wf, 0, 0, bf,
                                             label, wv, k_out, kemb16);
  }

  if (t1 || t2)
    attn_kernel<1><<<512, 256, 0, stream>>>(wv, wv16, query, k_out,
                                            kemb16, praw);
  else
    attn_kernel<0><<<512, 256, 0, stream>>>(wv, wv16, query, k_out,
                                            kemb16, praw);

  proj_kernel<<<192, 256, 0, stream>>>(praw, Wc, bc, p_out);
}

// Round 5
// 366.884 us; speedup vs baseline: 1.2270x; 1.2270x over previous
//
#include <hip/hip_runtime.h>

typedef unsigned short u16;
typedef unsigned int u32;
typedef __bf16 bf16x8 __attribute__((ext_vector_type(8)));
typedef float f32x4 __attribute__((ext_vector_type(4)));

#if defined(__has_builtin)
#  if __has_builtin(__builtin_amdgcn_cvt_pk_bf16_f32)
#    define PK_BF16 1
#  endif
#endif

__device__ __forceinline__ u16 f2bu(float f){
  u32 u = __float_as_uint(f);
  return (u16)((u + 0x7fffu + ((u >> 16) & 1u)) >> 16);
}
__device__ __forceinline__ float b2f(u16 u){
  union { float f; u32 i; } v; v.i = ((u32)u) << 16; return v.f;
}
__device__ __forceinline__ u32 pkbf(float a, float b){
#ifdef PK_BF16
  typedef __bf16 bf16x2 __attribute__((ext_vector_type(2)));
  union { bf16x2 h; u32 u; } c;
  c.h = __builtin_amdgcn_cvt_pk_bf16_f32(a, b);
  return c.u;
#else
  return (u32)f2bu(a) | ((u32)f2bu(b) << 16);
#endif
}
// async global->LDS, 16B per lane; LDS dest = wave-uniform base + lane*16
__device__ __forceinline__ void glds16(const u16* g, u16* l){
  __builtin_amdgcn_global_load_lds(
      (const __attribute__((address_space(1))) void*)g,
      (__attribute__((address_space(3))) void*)l, 16, 0, 0);
}
__device__ __forceinline__ void glds16f(const float* g, float* l){
  __builtin_amdgcn_global_load_lds(
      (const __attribute__((address_space(1))) void*)g,
      (__attribute__((address_space(3))) void*)l, 16, 0, 0);
}

// ---------------------------------------------------------------------------
// prep_wc: Wc[384][320] bf16 = Wp + 1e-5*Wm (zero padded), bc[384] f32
// ---------------------------------------------------------------------------
__global__ __launch_bounds__(256) void prep_wc(
    const float* __restrict__ Wp, const float* __restrict__ bp,
    const float* __restrict__ Wm, const float* __restrict__ bm,
    u16* __restrict__ Wc, float* __restrict__ bc)
{
  int idx = blockIdx.x * 256 + threadIdx.x;   // bf16-pair index
  if (idx < 384 * 160) {
    int n = idx / 160, k = (idx % 160) * 2;
    float v0 = 0.f, v1 = 0.f;
    if (n < 300 && k < 300) {
      v0 = Wp[n * 300 + k]     + 1e-5f * Wm[n * 300 + k];
      v1 = Wp[n * 300 + k + 1] + 1e-5f * Wm[n * 300 + k + 1];
    }
    ((u32*)Wc)[idx] = pkbf(v0, v1);
    if (idx < 384) bc[idx] = (idx < 300) ? bp[idx] + 1e-5f * bm[idx] : 0.f;
  }
}

// ---------------------------------------------------------------------------
// prep_wv16: wv16[30000][320] bf16 copy of wv (cols 300..319 zero)
// ---------------------------------------------------------------------------
__global__ __launch_bounds__(256) void prep_wv16(
    const float* __restrict__ wv, u16* __restrict__ wv16)
{
  int idx = blockIdx.x * 256 + threadIdx.x;   // pair index
  if (idx < 30000 * 160) {
    int row = idx / 160, k = (idx % 160) * 2;
    float v0 = 0.f, v1 = 0.f;
    if (k < 300) {
      v0 = wv[(size_t)row * 300 + k];
      v1 = wv[(size_t)row * 300 + k + 1];
    }
    ((u32*)wv16)[idx] = pkbf(v0, v1);
  }
}

// ---------------------------------------------------------------------------
// prep_wf16: Wf[300][2048] f32 -> Wf16[384][2048] bf16 (rows 300..383 zero)
// ---------------------------------------------------------------------------
__global__ __launch_bounds__(256) void prep_wf16(
    const float* __restrict__ Wf, u16* __restrict__ Wf16)
{
  int i = blockIdx.x * 256 + threadIdx.x;   // pair index, 384*1024 total
  if (i < 384 * 1024) {
    int row = i >> 10, c2 = (i & 1023) * 2;
    float v0 = 0.f, v1 = 0.f;
    if (row < 300) {
      v0 = Wf[(size_t)row * 2048 + c2];
      v1 = Wf[(size_t)row * 2048 + c2 + 1];
    }
    ((u32*)Wf16)[i] = pkbf(v0, v1);
  }
}

// ---------------------------------------------------------------------------
// gemm0 fallback (no workspace): f32 sources, cvt in staging, 128x128 tile.
// ---------------------------------------------------------------------------
template <int GLDS>
__global__ __launch_bounds__(256) void gemm0_kernel(
    const float* __restrict__ A, const float* __restrict__ B,
    const u16* __restrict__ Af16, const u16* __restrict__ Bf16,
    const float* __restrict__ bias,
    const int* __restrict__ label, const float* __restrict__ wv,
    float* __restrict__ C, u16* __restrict__ kemb16)
{
  __shared__ __align__(16) u16 As[128 * 32];
  __shared__ __align__(16) u16 Bs[128 * 32];
  const int lda = 2048, K = 2048, nbn = 3, nsrc = 300;
  int t = threadIdx.x;
  int bm = (blockIdx.x / nbn) * 128;
  int bn = (blockIdx.x % nbn) * 128;
  int lane = t & 63, w = t >> 6;
  int wm = (w >> 1) * 64, wn = (w & 1) * 64;

  f32x4 acc[4][4];
  for (int i = 0; i < 4; i++)
    for (int j = 0; j < 4; j++)
      for (int r = 0; r < 4; r++) acc[i][j][r] = 0.f;

  int mrow = lane & 15, q = lane >> 4;

  for (int kk = 0; kk < K; kk += 32) {
    #pragma unroll
    for (int p = 0; p < 2; p++) {
      int idx = t + p * 256;
      int row = idx >> 2, ch = idx & 3;
      int brow = bn + row;
      if (brow >= nsrc) brow = 0;  // clamp; masked at store
      const float4* ap = (const float4*)&A[(size_t)(bm + row) * lda + kk + ch * 8];
      float4 a0 = ap[0], a1 = ap[1];
      const float4* bpp = (const float4*)&B[(size_t)brow * lda + kk + ch * 8];
      float4 b0 = bpp[0], b1 = bpp[1];
      union { u32 u[4]; uint4 v; } pa, pb;
      pa.u[0] = pkbf(a0.x, a0.y); pa.u[1] = pkbf(a0.z, a0.w);
      pa.u[2] = pkbf(a1.x, a1.y); pa.u[3] = pkbf(a1.z, a1.w);
      pb.u[0] = pkbf(b0.x, b0.y); pb.u[1] = pkbf(b0.z, b0.w);
      pb.u[2] = pkbf(b1.x, b1.y); pb.u[3] = pkbf(b1.z, b1.w);
      *(uint4*)&As[idx * 8] = pa.v;
      *(uint4*)&Bs[idx * 8] = pb.v;
    }
    __syncthreads();

    bf16x8 af[4], bfr[4];
    #pragma unroll
    for (int i = 0; i < 4; i++)
      af[i] = *(const bf16x8*)&As[(wm + i * 16 + mrow) * 32 + q * 8];
    #pragma unroll
    for (int j = 0; j < 4; j++)
      bfr[j] = *(const bf16x8*)&Bs[(wn + j * 16 + mrow) * 32 + q * 8];
    #pragma unroll
    for (int i = 0; i < 4; i++)
      #pragma unroll
      for (int j = 0; j < 4; j++)
        acc[i][j] = __builtin_amdgcn_mfma_f32_16x16x32_bf16(
            af[i], bfr[j], acc[i][j], 0, 0, 0);
    __syncthreads();
  }

  // epilogue: C/D layout col=lane&15, row=(lane>>4)*4+reg
  #pragma unroll
  for (int i = 0; i < 4; i++)
    #pragma unroll
    for (int j = 0; j < 4; j++) {
      int col = bn + wn + j * 16 + (lane & 15);
      int rb = bm + wm + i * 16 + (lane >> 4) * 4;
      #pragma unroll
      for (int r = 0; r < 4; r++) {
        int m = rb + r;
        if (col < 300) {
          float v = acc[i][j][r];
          v += bias[col] + wv[(size_t)label[m] * 300 + col];
          C[(size_t)m * 300 + col] = v;
          if (kemb16) kemb16[(size_t)m * 320 + col] = f2bu(v);
        } else if (kemb16 && col < 320) {
          kemb16[(size_t)m * 320 + col] = 0;
        }
      }
    }
}

// ---------------------------------------------------------------------------
// gemm0 v5: k_emb = feature @ Wf16^T + bf + wv[label]
//   SINGLE-WAVE workgroups + counted-vmcnt pipeline (T4 without barriers).
//   Post-mortem v3/v4: v3's per-K-step __syncthreads = vmcnt(0) drain
//   (4700 cyc/iter); v4's per-lane fragment global loads uncoalesced +
//   no pipelining (8400 cyc/iter). Fix: keep m97-style glds staging (the
//   load shape that works) but make each 64-lane wave OWN its 64x64 tile:
//   no __syncthreads exists, next tile's 12 glds fly while current tile
//   computes, and `s_waitcnt vmcnt(12)` (never 0) is the only wait.
//   - A staged raw f32 (no prep pass), XOR-swizzled (v3's verified scheme:
//     pre-swizzled global source + swizzled LDS read), cvt_pk on read.
//   - B bf16 from prep_wf16, linear LDS.
//   - Grid 1280 = 256 M-tiles x 5 N-tiles = 5 waves/CU (LDS 24KB/block).
//   - XCD grouping: XCD x owns M rows [x*2048, (x+1)*2048): the 5 sibling
//     N-blocks of each M-panel co-run on one XCD -> A re-reads hit its L2.
// ---------------------------------------------------------------------------
__global__ __launch_bounds__(64) void gemm0v5_kernel(
    const float* __restrict__ A, const u16* __restrict__ Bf16,
    const float* __restrict__ bias, const int* __restrict__ label,
    const float* __restrict__ wv, float* __restrict__ C,
    u16* __restrict__ kemb16)
{
  __shared__ __align__(16) float As[2][64 * 32];   // 2 x 8KB
  __shared__ __align__(16) u16  Bs[2][64 * 32];    // 2 x 4KB
  int lane = threadIdx.x;                 // single wave
  int g = blockIdx.x;
  int xcd = g & 7, loc = g >> 3;          // 160 locs per XCD
  int mloc = loc / 5, nn = loc % 5;       // 32 M-panels x 5 N per XCD
  int bm = (xcd * 32 + mloc) * 64;
  int bn = nn * 64;
  int mrow = lane & 15, q = lane >> 4;

  f32x4 acc[4][4];
  #pragma unroll
  for (int i = 0; i < 4; i++)
    #pragma unroll
    for (int j = 0; j < 4; j++)
      #pragma unroll
      for (int r = 0; r < 4; r++) acc[i][j][r] = 0.f;

  // staging geometry:
  //  A: 8 glds, each covers 8 rows x 32 f32 (lane -> row lane>>3, 16B chunk
  //     lane&7). Source chunk pre-swizzled by ^row so LDS[r][c]=G[r][c^(r&7)].
  //  B: 4 glds, each covers 16 rows x 32 bf16 (row lane>>2, chunk lane&3).
  int rlA = lane >> 3, chA = lane & 7;
  int rlB = lane >> 2, chB = lane & 3;
  const float* gA = &A[(size_t)(bm + rlA) * 2048 + ((chA ^ rlA) << 2)];
  const u16*   gB = &Bf16[(size_t)(bn + rlB) * 2048 + (chB << 3)];

#define STAGE_V5(buf, kk) do {                                          \
    _Pragma("unroll")                                                   \
    for (int p = 0; p < 8; p++)                                         \
      glds16f(gA + (size_t)p * 8 * 2048 + (kk), &As[buf][(p * 8) * 32]);\
    _Pragma("unroll")                                                   \
    for (int p = 0; p < 4; p++)                                         \
      glds16(gB + (size_t)p * 16 * 2048 + (kk), &Bs[buf][(p * 16) * 32]);\
  } while (0)

  STAGE_V5(0, 0);

  for (int it = 0; it < 64; ++it) {
    int cur = it & 1;
    if (it < 63) {
      STAGE_V5(cur ^ 1, (it + 1) * 32);        // 12 loads fly over compute
      asm volatile("s_waitcnt vmcnt(12)" ::: "memory");  // prev tile landed
    } else {
      asm volatile("s_waitcnt vmcnt(0)" ::: "memory");
    }
    __builtin_amdgcn_sched_barrier(0);

    bf16x8 af[4], bfr[4];
    #pragma unroll
    for (int i = 0; i < 4; i++) {
      int r = i * 16 + mrow;
      int c0 = ((2 * q) ^ (r & 7)) * 4;        // swizzled read (matches src)
      int c1 = ((2 * q + 1) ^ (r & 7)) * 4;
      f32x4 x = *(const f32x4*)&As[cur][r * 32 + c0];
      f32x4 y = *(const f32x4*)&As[cur][r * 32 + c1];
      union { u32 u[4]; bf16x8 h; } cc;
      cc.u[0] = pkbf(x[0], x[1]); cc.u[1] = pkbf(x[2], x[3]);
      cc.u[2] = pkbf(y[0], y[1]); cc.u[3] = pkbf(y[2], y[3]);
      af[i] = cc.h;
    }
    #pragma unroll
    for (int j = 0; j < 4; j++)
      bfr[j] = *(const bf16x8*)&Bs[cur][(j * 16 + mrow) * 32 + q * 8];
    #pragma unroll
    for (int i = 0; i < 4; i++)
      #pragma unroll
      for (int j = 0; j < 4; j++)
        acc[i][j] = __builtin_amdgcn_mfma_f32_16x16x32_bf16(
            af[i], bfr[j], acc[i][j], 0, 0, 0);
  }
#undef STAGE_V5

  // epilogue: C/D layout col=lane&15, row=(lane>>4)*4+reg
  #pragma unroll
  for (int i = 0; i < 4; i++)
    #pragma unroll
    for (int j = 0; j < 4; j++) {
      int col = bn + j * 16 + (lane & 15);
      int rb = bm + i * 16 + (lane >> 4) * 4;
      #pragma unroll
      for (int r = 0; r < 4; r++) {
        int m = rb + r;
        if (col < 300) {
          float v = acc[i][j][r] + bias[col] + wv[(size_t)label[m] * 300 + col];
          C[(size_t)m * 300 + col] = v;
          kemb16[(size_t)m * 320 + col] = f2bu(v);
        } else {            // bn <= 256 so col < 320 always
          kemb16[(size_t)m * 320 + col] = 0;
        }
      }
    }
}

// ---------------------------------------------------------------------------
// attn (MFMA): block = (b, half of 16 y) -> 192 qwords x 64 keys, K=320.
// ke bf16 in LDS stride 344; A frags straight from wv16 (FULL) with depth-1
// prefetch, or from wv f32 (fallback). Softmax via shfl (1/sum-exp identity),
// word-softmax/5, vectorized p_raw -> praw bf16 [row][320].
// ---------------------------------------------------------------------------
#define KES 344
template <int FULL>
__global__ __launch_bounds__(256) void attn_kernel(
    const float* __restrict__ wv, const u16* __restrict__ wv16,
    const int* __restrict__ query,
    const float* __restrict__ kout, const u16* __restrict__ kemb16,
    u16* __restrict__ praw)
{
  __shared__ __align__(16) u16 ke[64 * KES];
  __shared__ __align__(16) int qoff[192];
  __shared__ __align__(16) float awd[192];
  __shared__ __align__(16) float wt[192];

  int blk = blockIdx.x, b = blk >> 1, bh = blk & 1;
  int t = threadIdx.x;
  int lane = t & 63, w = t >> 6;

  if (FULL) {
    for (int i = t; i < 2560; i += 256) {          // uint4 chunks of 8 cols
      int row = i / 40, ch = i % 40;
      *(uint4*)&ke[row * KES + ch * 8] =
          *(const uint4*)&kemb16[(size_t)(b * 64 + row) * 320 + ch * 8];
    }
  } else {
    for (int i = t; i < 4800; i += 256) {          // float4 chunks of 4 cols
      int row = i / 75, c4 = i % 75;
      float4 v = *(const float4*)&kout[(size_t)(b * 64 + row) * 300 + c4 * 4];
      *(u32*)&ke[row * KES + c4 * 4]     = pkbf(v.x, v.y);
      *(u32*)&ke[row * KES + c4 * 4 + 2] = pkbf(v.z, v.w);
    }
    for (int i = t; i < 640; i += 256) {           // zero cols 300..319
      int row = i / 10, c2 = i % 10;
      *(u32*)&ke[row * KES + 300 + c2 * 2] = 0;
    }
  }
  if (t < 192)
    qoff[t] = query[b * 384 + bh * 192 + t] * (FULL ? 320 : 300);
  __syncthreads();

  int mrow = lane & 15, q = lane >> 4;
  f32x4 acc[3][4];
  #pragma unroll
  for (int i = 0; i < 3; i++)
    #pragma unroll
    for (int j = 0; j < 4; j++)
      #pragma unroll
      for (int r = 0; r < 4; r++) acc[i][j][r] = 0.f;

  int base[3];
  #pragma unroll
  for (int i = 0; i < 3; i++) base[i] = qoff[w * 48 + i * 16 + mrow];
  int keb = mrow * KES + q * 8;

  bf16x8 afn[3];
  #pragma unroll
  for (int i = 0; i < 3; i++) {
    if (FULL)
      afn[i] = *(const bf16x8*)&wv16[(size_t)base[i] + q * 8];
  }

  for (int k0 = 0; k0 < 320; k0 += 32) {
    bf16x8 af[3], bfr[4];
    #pragma unroll
    for (int i = 0; i < 3; i++) {
      if (FULL) {
        af[i] = afn[i];
        if (k0 + 32 < 320)      // depth-1 prefetch
          afn[i] = *(const bf16x8*)&wv16[(size_t)base[i] + k0 + 32 + q * 8];
      } else {
        int cs = k0 + q * 8;
        union { u32 u[4]; bf16x8 h; } c;
        if (cs + 8 <= 300) {
          const float4* p = (const float4*)&wv[(size_t)base[i] + cs];
          float4 x = p[0], y = p[1];
          c.u[0] = pkbf(x.x, x.y); c.u[1] = pkbf(x.z, x.w);
          c.u[2] = pkbf(y.x, y.y); c.u[3] = pkbf(y.z, y.w);
        } else if (cs < 300) {   // cs == 296
          float4 x = *(const float4*)&wv[(size_t)base[i] + 296];
          c.u[0] = pkbf(x.x, x.y); c.u[1] = pkbf(x.z, x.w);
          c.u[2] = 0; c.u[3] = 0;
        } else {
          c.u[0] = 0; c.u[1] = 0; c.u[2] = 0; c.u[3] = 0;
        }
        af[i] = c.h;
      }
    }
    #pragma unroll
    for (int j = 0; j < 4; j++)
      bfr[j] = *(const bf16x8*)&ke[j * 16 * KES + keb + k0];
    #pragma unroll
    for (int i = 0; i < 3; i++)
      #pragma unroll
      for (int j = 0; j < 4; j++)
        acc[i][j] = __builtin_amdgcn_mfma_f32_16x16x32_bf16(
            af[i], bfr[j], acc[i][j], 0, 0, 0);
  }

  // per-word softmax-over-keys: a_w = 1/sum_k exp(scale*(att-max))
  const float scale = 0.05773502691896258f;   // 1/sqrt(300)
  #pragma unroll
  for (int i = 0; i < 3; i++)
    #pragma unroll
    for (int r = 0; r < 4; r++) {
      float mx = fmaxf(fmaxf(acc[i][0][r], acc[i][1][r]),
                       fmaxf(acc[i][2][r], acc[i][3][r]));
      #pragma unroll
      for (int d = 1; d < 16; d <<= 1)
        mx = fmaxf(mx, __shfl_xor(mx, d));
      float se = 0.f;
      #pragma unroll
      for (int j = 0; j < 4; j++)
        se += __expf((acc[i][j][r] - mx) * scale);
      #pragma unroll
      for (int d = 1; d < 16; d <<= 1)
        se += __shfl_xor(se, d);
      if (mrow == 0) {
        int wl = w * 48 + i * 16 + q * 4 + r;
        awd[wl] = (qoff[wl] == 0) ? -3.402823466e38f : (1.0f / se);
      }
    }
  __syncthreads();

  // per-y softmax over 12 words, /5
  if (t < 16) {
    int yb = t * 12;
    float m2 = -3.402823466e38f;
    for (int i = 0; i < 12; i++) m2 = fmaxf(m2, awd[yb + i]);
    float e[12], s2 = 0.f;
    for (int i = 0; i < 12; i++) { e[i] = __expf(awd[yb + i] - m2); s2 += e[i]; }
    float inv = 0.2f / s2;
    for (int i = 0; i < 12; i++) wt[yb + i] = e[i] * inv;
  }
  __syncthreads();

  // p_raw: wave w -> 4 y's
  #pragma unroll
  for (int yy = 0; yy < 4; yy++) {
    int yl = w * 4 + yy;
    int row = b * 32 + bh * 16 + yl;
    if (FULL) {
      if (lane < 40) {     // lane covers 8 cols; 40*8 = 320
        float s[8];
        #pragma unroll
        for (int e = 0; e < 8; e++) s[e] = 0.f;
        for (int i = 0; i < 12; i++) {
          float g = wt[yl * 12 + i];
          union { uint4 v; u16 h[8]; } qv;
          qv.v = *(const uint4*)&wv16[(size_t)qoff[yl * 12 + i] + lane * 8];
          #pragma unroll
          for (int e = 0; e < 8; e++) s[e] += g * b2f(qv.h[e]);
        }
        union { uint4 v; u16 h[8]; } o;
        #pragma unroll
        for (int e = 0; e < 8; e++) o.h[e] = f2bu(s[e]);
        *(uint4*)&praw[(size_t)row * 320 + lane * 8] = o.v;
      }
    } else {
      #pragma unroll
      for (int c = 0; c < 5; c++) {
        int d = c * 64 + lane;
        float s = 0.f;
        if (d < 300)
          for (int i = 0; i < 12; i++)
            s += wt[yl * 12 + i] * wv[(size_t)qoff[yl * 12 + i] + d];
        praw[(size_t)row * 320 + d] = f2bu(s);
      }
    }
  }
}

// ---------------------------------------------------------------------------
// proj (MFMA + glds): p_emb[8192][300] = praw(bf16) @ Wc(bf16)^T + bc -> f32
// ---------------------------------------------------------------------------
__global__ __launch_bounds__(256) void proj_kernel(
    const u16* __restrict__ praw, const u16* __restrict__ Wc,
    const float* __restrict__ bc, float* __restrict__ P)
{
  __shared__ __align__(16) u16 As[128 * 32];
  __shared__ __align__(16) u16 Bs[128 * 32];
  int t = threadIdx.x;
  int bm = (blockIdx.x / 3) * 128;
  int bn = (blockIdx.x % 3) * 128;
  int lane = t & 63, w = t >> 6;
  int wm = (w >> 1) * 64, wn = (w & 1) * 64;

  f32x4 acc[4][4];
  for (int i = 0; i < 4; i++)
    for (int j = 0; j < 4; j++)
      for (int r = 0; r < 4; r++) acc[i][j][r] = 0.f;

  int mrow = lane & 15, q = lane >> 4;

  for (int kk = 0; kk < 320; kk += 32) {
    int r0 = w * 32;
    int rl = lane >> 2, ch = lane & 3;
    #pragma unroll
    for (int p = 0; p < 2; p++) {
      int row = r0 + p * 16 + rl;
      glds16(&praw[(size_t)(bm + row) * 320 + kk + ch * 8],
             &As[(r0 + p * 16) * 32]);
      glds16(&Wc[(size_t)(bn + row) * 320 + kk + ch * 8],
             &Bs[(r0 + p * 16) * 32]);
    }
    __syncthreads();

    bf16x8 af[4], bfr[4];
    #pragma unroll
    for (int i = 0; i < 4; i++)
      af[i] = *(const bf16x8*)&As[(wm + i * 16 + mrow) * 32 + q * 8];
    #pragma unroll
    for (int j = 0; j < 4; j++)
      bfr[j] = *(const bf16x8*)&Bs[(wn + j * 16 + mrow) * 32 + q * 8];
    #pragma unroll
    for (int i = 0; i < 4; i++)
      #pragma unroll
      for (int j = 0; j < 4; j++)
        acc[i][j] = __builtin_amdgcn_mfma_f32_16x16x32_bf16(
            af[i], bfr[j], acc[i][j], 0, 0, 0);
    __syncthreads();
  }

  #pragma unroll
  for (int i = 0; i < 4; i++)
    #pragma unroll
    for (int j = 0; j < 4; j++) {
      int col = bn + wn + j * 16 + (lane & 15);
      if (col >= 300) continue;
      int rb = bm + wm + i * 16 + (lane >> 4) * 4;
      #pragma unroll
      for (int r = 0; r < 4; r++)
        P[(size_t)(rb + r) * 300 + col] = acc[i][j][r] + bc[col];
    }
}

// ---------------------------------------------------------------------------
extern "C" void kernel_launch(void* const* d_in, const int* in_sizes, int n_in,
                              void* d_out, int out_size, void* d_ws,
                              size_t ws_size, hipStream_t stream)
{
  const float* wv      = (const float*)d_in[0];   // [30000,300] f32
  const float* Wf      = (const float*)d_in[1];   // [300,2048]  f32
  const float* bf      = (const float*)d_in[2];   // [300]       f32
  const float* Wp      = (const float*)d_in[3];   // [300,300]   f32
  const float* bp      = (const float*)d_in[4];   // [300]       f32
  const float* Wm      = (const float*)d_in[5];   // [300,300]   f32
  const float* bm      = (const float*)d_in[6];   // [300]       f32
  const float* feature = (const float*)d_in[7];   // [256,64,2048] f32
  const int*   query   = (const int*)d_in[8];     // [256,32,12]
  const int*   label   = (const int*)d_in[9];     // [256,64]

  float* out   = (float*)d_out;     // f32 output
  float* p_out = out;               // p_emb: 8192*300
  float* k_out = out + 2457600;     // k_emb: 16384*300

  char* ws = (char*)d_ws;
  // T2 layout (feature16 slot unused - gemm0v5 stages f32 directly):
  //   (unused):           0  (67,108,864)
  //   wv16:      67,108,864  (19,200,000)
  //   kemb16:    86,308,864  (10,485,760)
  //   praw:      96,794,624  ( 5,242,880)
  //   Wc:       102,037,504  (   245,760)
  //   Wf16:     102,283,264  ( 1,572,864)
  //   bc:       103,856,128  (     1,536)
  int t2 = ws_size >= (size_t)103857664;
  int t1 = ws_size >= (size_t)35175936;
  u16 *wf16 = 0, *wv16 = 0, *kemb16 = 0, *praw, *Wc;
  float* bc;
  if (t2) {
    wv16   = (u16*)(ws + 67108864);
    kemb16 = (u16*)(ws + 86308864);
    praw   = (u16*)(ws + 96794624);
    Wc     = (u16*)(ws + 102037504);
    wf16   = (u16*)(ws + 102283264);
    bc     = (float*)(ws + 103856128);
  } else if (t1) {
    wv16   = (u16*)ws;                    // 19,200,000
    kemb16 = (u16*)(ws + 19200000);       // 10,485,760
    praw   = (u16*)(ws + 29685760);       //  5,242,880
    Wc     = (u16*)(ws + 34928640);       //    245,760
    bc     = (float*)(ws + 35174400);
  } else {
    praw   = (u16*)ws;
    Wc     = (u16*)(ws + 5242880);
    bc     = (float*)(ws + 5488640);
  }

  prep_wc<<<240, 256, 0, stream>>>(Wp, bp, Wm, bm, Wc, bc);
  if (t1 || t2)
    prep_wv16<<<18750, 256, 0, stream>>>(wv, wv16);
  if (t2) {
    prep_wf16<<<1536, 256, 0, stream>>>(Wf, wf16);
    gemm0v5_kernel<<<1280, 64, 0, stream>>>(feature, wf16, bf,
                                            label, wv, k_out, kemb16);
  } else {
    gemm0_kernel<0><<<384, 256, 0, stream>>>(feature, Wf, 0, 0, bf,
                                             label, wv, k_out, kemb16);
  }

  if (t1 || t2)
    attn_kernel<1><<<512, 256, 0, stream>>>(wv, wv16, query, k_out,
                                            kemb16, praw);
  else
    attn_kernel<0><<<512, 256, 0, stream>>>(wv, wv16, query, k_out,
                                            kemb16, praw);

  proj_kernel<<<192, 256, 0, stream>>>(praw, Wc, bc, p_out);
}